// Round 4
// baseline (18922.047 us; speedup 1.0000x reference)
//
#include <hip/hip_runtime.h>

#define SEQL 256
#define BATCH 64
#define HID 1024
#define NLAY 5
#define NBLK 32
#define NCLS 32000

typedef __attribute__((__ext_vector_type__(8))) short s16x8;
typedef __attribute__((__ext_vector_type__(4))) float f32x4;

__device__ __forceinline__ unsigned short f2bf(float f) {
  unsigned u = __float_as_uint(f);
  u = u + 0x7fffu + ((u >> 16) & 1u);
  return (unsigned short)(u >> 16);
}
__device__ __forceinline__ float bf2f(unsigned short s) {
  return __uint_as_float(((unsigned)s) << 16);
}
__device__ __forceinline__ float sigm(float x) { return 1.f / (1.f + __expf(-x)); }
__device__ __forceinline__ float tanh_f(float x) {
  float a = fabsf(x);
  float e = __expf(-2.f * a);
  float t = (1.f - e) / (1.f + e);
  return x < 0.f ? -t : t;
}

__device__ __forceinline__ void llds16(const void* g, void* l) {
  __builtin_amdgcn_global_load_lds((const __attribute__((address_space(1))) unsigned int*)g,
                                   (__attribute__((address_space(3))) unsigned int*)l,
                                   16, 0, 0);
}

#define AFENCE asm volatile("" ::: "memory")
#define VW0 asm volatile("s_waitcnt vmcnt(0)" ::: "memory")
#define LW0 asm volatile("s_waitcnt lgkmcnt(0)" ::: "memory")
#define SBAR __builtin_amdgcn_s_barrier()

// ---------------- weight packing: fp32 Wx/Wh -> bf16 MFMA-B fragments ----------------
// Wp index: ((((l*64 + j)*4 + g)*64 + k0)*64 + lane)*8 + i   (bf16 units)
// lane element i: k = k0*32 + (lane>>4)*8 + i, col h = j*16 + (lane&15)
// rows k<1024 from Wx[l][g], rows >=1024 from Wh[l][g].
__global__ void pack_k(const float* __restrict__ Wx, const float* __restrict__ Wh,
                       unsigned short* __restrict__ Wp) {
  int bid = blockIdx.x;
  int k0 = bid & 63;
  int g = (bid >> 6) & 3;
  int j = (bid >> 8) & 63;
  int l = bid >> 14;
  int lane = threadIdx.x;
  int h = j * 16 + (lane & 15);
  int kb = k0 * 32 + (lane >> 4) * 8;
  const float* src;
  if (kb < 1024) src = Wx + ((size_t)((l * 4 + g) * 1024 + kb)) * 1024 + h;
  else           src = Wh + ((size_t)((l * 4 + g) * 1024 + (kb - 1024))) * 1024 + h;
  unsigned short o[8];
#pragma unroll
  for (int i = 0; i < 8; ++i) o[i] = f2bf(src[(size_t)i * 1024]);
  uint4 v;
  v.x = (unsigned)o[0] | ((unsigned)o[1] << 16);
  v.y = (unsigned)o[2] | ((unsigned)o[3] << 16);
  v.z = (unsigned)o[4] | ((unsigned)o[5] << 16);
  v.w = (unsigned)o[6] | ((unsigned)o[7] << 16);
  *(uint4*)(Wp + (((size_t)bid * 64 + lane) * 8)) = v;
}

// ---------------- embedding gather ----------------
__global__ void embed_k(const int* __restrict__ X, const float* __restrict__ emb,
                        unsigned short* __restrict__ hsA) {
  int sb = blockIdx.x;  // t*64 + b
  int t = sb >> 6, b = sb & 63;
  int row = X[b * SEQL + t];
  float4 v = ((const float4*)(emb + (size_t)row * HID))[threadIdx.x];
  unsigned short o0 = f2bf(v.x), o1 = f2bf(v.y), o2 = f2bf(v.z), o3 = f2bf(v.w);
  uint2 pk;
  pk.x = (unsigned)o0 | ((unsigned)o1 << 16);
  pk.y = (unsigned)o2 | ((unsigned)o3 << 16);
  ((uint2*)(hsA + (size_t)sb * HID))[threadIdx.x] = pk;
}

// ---------------- persistent fused LSTM ----------------
// 32 blocks x 512 threads (8 waves). Block jj owns hidden cols [jj*32, jj*32+32)
// (= packed col-groups 2jj, 2jj+1). Wave w: gate g = w&3, batch-half mh = w>>2,
// computes a 32x32 output tile (2 m-tiles x 2 n-tiles), K = 2048 over 4 phases.
// Two 64KB LDS staging buffers ping-pong; cell state in registers;
// pre-activations exchanged via a 17KB LDS buffer in two batch-half passes.
extern __shared__ char smem[];

__device__ __forceinline__ void stage8(const char* slab, int half, char* wb,
                                       int wave, int lane) {
#pragma unroll
  for (int it = 0; it < 8; ++it) {
    int row = wave + it * 8;
    int c = lane ^ (row & 7);
    llds16(slab + row * 2048 + half * 1024 + c * 16, wb + row * 1024);
  }
}

__device__ __forceinline__ void ph2(const unsigned short* w0, const unsigned short* w1,
                                    const char* rb, const char* slab, int half, char* wb,
                                    bool dostage, int hl, int ksub, int lane, int wave,
                                    int mh, f32x4 (&acc)[2][2]) {
  if (dostage) stage8(slab, half, wb, wave, lane);
  const char* a0b = rb + (mh * 32 + hl) * 1024;
#pragma unroll 4
  for (int k0 = 0; k0 < 16; ++k0) {
    s16x8 b0 = *(const s16x8*)(w0 + (k0 << 9) + (lane << 3));
    s16x8 b1 = *(const s16x8*)(w1 + (k0 << 9) + (lane << 3));
    int so = ((k0 * 4 + ksub) ^ (hl & 7)) << 4;
    s16x8 a0 = *(const s16x8*)(a0b + so);
    s16x8 a1 = *(const s16x8*)(a0b + 16384 + so);
    acc[0][0] = __builtin_amdgcn_mfma_f32_16x16x32_bf16(a0, b0, acc[0][0], 0, 0, 0);
    acc[1][0] = __builtin_amdgcn_mfma_f32_16x16x32_bf16(a1, b0, acc[1][0], 0, 0, 0);
    acc[0][1] = __builtin_amdgcn_mfma_f32_16x16x32_bf16(a0, b1, acc[0][1], 0, 0, 0);
    acc[1][1] = __builtin_amdgcn_mfma_f32_16x16x32_bf16(a1, b1, acc[1][1], 0, 0, 0);
  }
}

__device__ __forceinline__ void pollflags(int* flags, int id, int lane) {
  if (id <= 0) return;
  int fi = (lane & 31) * 4;
  for (;;) {
    int v = __hip_atomic_load(&flags[fi], __ATOMIC_RELAXED, __HIP_MEMORY_SCOPE_AGENT);
    if (__all(v >= id)) break;
    __builtin_amdgcn_s_sleep(1);
  }
}

__global__ void __launch_bounds__(512, 1)
lstm_pers(const unsigned short* __restrict__ Wp, const float* __restrict__ bias,
          unsigned short* hsA, unsigned short* hsB, int* flags) {
  const int jj = blockIdx.x;  // 0..31
  const int tid = threadIdx.x;
  const int wave = tid >> 6;
  const int lane = tid & 63;
  const int g = wave & 3;
  const int mh = wave >> 2;
  const int hl = lane & 15;
  const int ksub = lane >> 4;
  char* B0 = smem;                        // 65536
  char* B1 = smem + 65536;                // 65536
  float* pre = (float*)(smem + 131072);   // [4][32][34] f32 = 17408

  // gate-thread mapping (stable across steps -> cell state in registers)
  const int gb = tid >> 4;        // batch row within half (0..31)
  const int gh = (tid & 15) * 2;  // hidden col pair base within block (0..30)

  for (int l = 0; l < NLAY; ++l) {
    const unsigned short* hin = (l & 1) ? hsB : hsA;
    unsigned short* hout = (l & 1) ? hsA : hsB;
    const unsigned short* wp0 = Wp + (size_t)(l * 64 + jj * 2) * 131072 + (size_t)g * 32768;
    const unsigned short* wp1 = wp0 + 131072;
    float bias0 = bias[(l * 4 + g) * 1024 + jj * 32 + hl];
    float bias1 = bias[(l * 4 + g) * 1024 + jj * 32 + 16 + hl];
    float creg[2][2] = {{0.f, 0.f}, {0.f, 0.f}};

    // layer entry: wave0 waits for previous layer complete, then all stage x_0
    if (wave == 0) pollflags(flags, l * 256, lane);
    AFENCE; SBAR;
    stage8((const char*)hin, 0, B0, wave, lane);
    stage8((const char*)hin, 1, B1, wave, lane);

    for (int t = 0; t < SEQL; ++t) {
      const char* xn = (const char*)hin + (size_t)(t + 1) * 131072;
      const bool pre_ = (t + 1 < SEQL);
      f32x4 acc[2][2];
#pragma unroll
      for (int m = 0; m < 2; ++m)
#pragma unroll
        for (int n = 0; n < 2; ++n) acc[m][n] = (f32x4){0.f, 0.f, 0.f, 0.f};

      if (t == 0) {
        VW0; SBAR;  // x_0 staged (both halves)
        ph2(wp0 + 0 * 8192, wp1 + 0 * 8192, B0, nullptr, 0, nullptr, false,
            hl, ksub, lane, wave, mh, acc);
        AFENCE; SBAR;  // all waves done reading B0
        // x-hi MFMA + stage x_1-lo -> B0
        ph2(wp0 + 1 * 8192, wp1 + 1 * 8192, B1, xn, 0, B0, pre_,
            hl, ksub, lane, wave, mh, acc);
      } else {
        const char* hp = (const char*)hout + (size_t)(t - 1) * 131072;
        // x-lo MFMA (B0 staged last step); wave0 polls concurrently
        ph2(wp0 + 0 * 8192, wp1 + 0 * 8192, B0, nullptr, 0, nullptr, false,
            hl, ksub, lane, wave, mh, acc);
        if (wave == 0) pollflags(flags, l * 256 + t, lane);
        VW0; SBAR;  // own x'-hi stage retired; B0 reads done; h_{t-1} visible
        // x-hi MFMA + stage h-lo -> B0
        ph2(wp0 + 1 * 8192, wp1 + 1 * 8192, B1, hp, 0, B0, true,
            hl, ksub, lane, wave, mh, acc);
        VW0; SBAR;  // h-lo landed; B1 reads done
        // h-lo MFMA + stage h-hi -> B1
        ph2(wp0 + 2 * 8192, wp1 + 2 * 8192, B0, hp, 1, B1, true,
            hl, ksub, lane, wave, mh, acc);
        VW0; SBAR;  // h-hi landed; B0 reads done
        // h-hi MFMA + stage x_{t+1}-lo -> B0
        ph2(wp0 + 3 * 8192, wp1 + 3 * 8192, B1, xn, 0, B0, pre_,
            hl, ksub, lane, wave, mh, acc);
      }

      // ---- epilogue + gates, two batch-half passes through pre ----
      // pass A: batch rows 0..31 (mh==0 waves' accumulators)
      if (mh == 0) {
#pragma unroll
        for (int m = 0; m < 2; ++m)
#pragma unroll
          for (int n = 0; n < 2; ++n)
#pragma unroll
            for (int r = 0; r < 4; ++r) {
              int row = m * 16 + ksub * 4 + r;
              pre[(g * 32 + row) * 34 + n * 16 + hl] = acc[m][n][r] + (n ? bias1 : bias0);
            }
      }
      LW0; SBAR;
      {
        unsigned short hw[2];
#pragma unroll
        for (int q = 0; q < 2; ++q) {
          int hh = gh + q;
          float pi = pre[(0 * 32 + gb) * 34 + hh];
          float pf = pre[(1 * 32 + gb) * 34 + hh];
          float po = pre[(2 * 32 + gb) * 34 + hh];
          float pg = pre[(3 * 32 + gb) * 34 + hh];
          float iv = sigm(pi), fv = sigm(pf), ov = sigm(po), gv = tanh_f(pg);
          float c = fv * creg[0][q] + iv * gv;
          creg[0][q] = c;
          hw[q] = f2bf(ov * tanh_f(c));
        }
        unsigned pk = (unsigned)hw[0] | ((unsigned)hw[1] << 16);
        unsigned* dst = (unsigned*)(hout + (size_t)(t * 64 + gb) * HID + jj * 32 + gh);
        __hip_atomic_store(dst, pk, __ATOMIC_RELAXED, __HIP_MEMORY_SCOPE_AGENT);
      }
      SBAR;  // all pass-A pre reads done
      // pass B: batch rows 32..63 (mh==1 waves' accumulators)
      if (mh == 1) {
#pragma unroll
        for (int m = 0; m < 2; ++m)
#pragma unroll
          for (int n = 0; n < 2; ++n)
#pragma unroll
            for (int r = 0; r < 4; ++r) {
              int row = m * 16 + ksub * 4 + r;
              pre[(g * 32 + row) * 34 + n * 16 + hl] = acc[m][n][r] + (n ? bias1 : bias0);
            }
      }
      LW0; SBAR;
      {
        unsigned short hw[2];
#pragma unroll
        for (int q = 0; q < 2; ++q) {
          int hh = gh + q;
          float pi = pre[(0 * 32 + gb) * 34 + hh];
          float pf = pre[(1 * 32 + gb) * 34 + hh];
          float po = pre[(2 * 32 + gb) * 34 + hh];
          float pg = pre[(3 * 32 + gb) * 34 + hh];
          float iv = sigm(pi), fv = sigm(pf), ov = sigm(po), gv = tanh_f(pg);
          float c = fv * creg[1][q] + iv * gv;
          creg[1][q] = c;
          hw[q] = f2bf(ov * tanh_f(c));
        }
        unsigned pk = (unsigned)hw[0] | ((unsigned)hw[1] << 16);
        unsigned* dst = (unsigned*)(hout + (size_t)(t * 64 + 32 + gb) * HID + jj * 32 + gh);
        __hip_atomic_store(dst, pk, __ATOMIC_RELAXED, __HIP_MEMORY_SCOPE_AGENT);
      }
      VW0;   // own h stores (both passes) acked; own x'-lo stage retired
      SBAR;  // => ALL waves' h stores globally visible
      if (tid == 0)
        __hip_atomic_store(&flags[jj * 4], l * 256 + t + 1, __ATOMIC_RELAXED,
                           __HIP_MEMORY_SCOPE_AGENT);
      // stage x_{t+1}-hi -> B1 (after flag; drained by next step's first VW0)
      if (pre_) stage8(xn, 1, B1, wave, lane);
    }
  }
}

// ---------------- output projection (fp32, K split 2-way) ----------------
__global__ void __launch_bounds__(256) proj_k(const unsigned short* __restrict__ hlast,
                                              const float* __restrict__ Whq,
                                              float* __restrict__ part) {
  __shared__ float hlds[64 * 128];
  int kh = blockIdx.x / 125;
  int nb = blockIdx.x % 125;
  int n = nb * 256 + threadIdx.x;
  float acc[64];
#pragma unroll
  for (int b = 0; b < 64; ++b) acc[b] = 0.f;
  for (int kc = 0; kc < 4; ++kc) {
    int kbase = kh * 512 + kc * 128;
    __syncthreads();
#pragma unroll
    for (int it = 0; it < 32; ++it) {
      int id = threadIdx.x + it * 256;
      int b = id >> 7, k = id & 127;
      hlds[b * 128 + k] = bf2f(hlast[(size_t)b * HID + kbase + k]);
    }
    __syncthreads();
    for (int k4 = 0; k4 < 32; ++k4) {
      float w0 = Whq[(size_t)(kbase + k4 * 4 + 0) * NCLS + n];
      float w1 = Whq[(size_t)(kbase + k4 * 4 + 1) * NCLS + n];
      float w2 = Whq[(size_t)(kbase + k4 * 4 + 2) * NCLS + n];
      float w3 = Whq[(size_t)(kbase + k4 * 4 + 3) * NCLS + n];
#pragma unroll
      for (int b = 0; b < 64; ++b) {
        float4 h4 = *(const float4*)&hlds[b * 128 + k4 * 4];
        acc[b] += h4.x * w0 + h4.y * w1 + h4.z * w2 + h4.w * w3;
      }
    }
  }
#pragma unroll
  for (int b = 0; b < 64; ++b)
    part[(size_t)kh * 64 * NCLS + (size_t)b * NCLS + n] = acc[b];
}

__global__ void combine_k(const float* __restrict__ part, const float* __restrict__ bq,
                          float* __restrict__ out) {
  int i = blockIdx.x * 256 + threadIdx.x;
  int n = i % NCLS;
  out[i] = part[i] + part[64 * NCLS + i] + bq[n];
}

extern "C" void kernel_launch(void* const* d_in, const int* in_sizes, int n_in,
                              void* d_out, int out_size, void* d_ws, size_t ws_size,
                              hipStream_t stream) {
  const int* X = (const int*)d_in[0];
  const float* emb = (const float*)d_in[1];
  const float* Wx = (const float*)d_in[2];
  const float* Wh = (const float*)d_in[3];
  const float* bias = (const float*)d_in[4];
  const float* Whq = (const float*)d_in[5];
  const float* bq = (const float*)d_in[6];
  float* out = (float*)d_out;
  char* ws = (char*)d_ws;

  const size_t WP_OFF = 0;                      // 83,886,080  packed weights bf16
  const size_t HSA_OFF = 83886080;              // 33,554,432  hs ping
  const size_t HSB_OFF = HSA_OFF + 33554432;    // 33,554,432  hs pong
  const size_t PART_OFF = HSB_OFF + 33554432;   // 16,384,000  proj partials
  const size_t FLAG_OFF = PART_OFF + 16384000;  // 4,096       barrier flags
  const size_t NEED = FLAG_OFF + 4096;
  if (ws_size < NEED) return;

  unsigned short* Wp = (unsigned short*)(ws + WP_OFF);
  unsigned short* hsA = (unsigned short*)(ws + HSA_OFF);
  unsigned short* hsB = (unsigned short*)(ws + HSB_OFF);
  float* part = (float*)(ws + PART_OFF);
  int* flags = (int*)(ws + FLAG_OFF);

  hipMemsetAsync(flags, 0, 64 * 16 * sizeof(int), stream);
  pack_k<<<81920, 64, 0, stream>>>(Wx, Wh, Wp);
  embed_k<<<16384, 256, 0, stream>>>(X, emb, hsA);
  (void)hipFuncSetAttribute(reinterpret_cast<const void*>(&lstm_pers),
                            hipFuncAttributeMaxDynamicSharedMemorySize, 148480);
  lstm_pers<<<NBLK, 512, 148480, stream>>>(Wp, bias, hsA, hsB, flags);
  const unsigned short* hlastp = hsB + (size_t)255 * BATCH * HID;  // layer 4, t=255
  proj_k<<<250, 256, 0, stream>>>(hlastp, Whq, part);
  combine_k<<<8000, 256, 0, stream>>>(part, bq, out);
}

// Round 5
// 4074.397 us; speedup vs baseline: 4.6441x; 4.6441x over previous
//
#include <hip/hip_runtime.h>

#define SEQL 256
#define BATCH 64
#define HID 1024
#define NLAY 5
#define NCLS 32000

typedef __attribute__((__ext_vector_type__(8))) short s16x8;
typedef __attribute__((__ext_vector_type__(4))) float f32x4;

__device__ __forceinline__ unsigned short f2bf(float f) {
  unsigned u = __float_as_uint(f);
  u = u + 0x7fffu + ((u >> 16) & 1u);
  return (unsigned short)(u >> 16);
}
__device__ __forceinline__ float bf2f(unsigned short s) {
  return __uint_as_float(((unsigned)s) << 16);
}
__device__ __forceinline__ float sigm(float x) { return 1.f / (1.f + __expf(-x)); }
__device__ __forceinline__ float tanh_f(float x) {
  float a = fabsf(x);
  float e = __expf(-2.f * a);
  float t = (1.f - e) / (1.f + e);
  return x < 0.f ? -t : t;
}

__device__ __forceinline__ void llds16(const void* g, void* l) {
  __builtin_amdgcn_global_load_lds((const __attribute__((address_space(1))) unsigned int*)g,
                                   (__attribute__((address_space(3))) unsigned int*)l,
                                   16, 0, 0);
}

#define AFENCE asm volatile("" ::: "memory")
#define VW0 asm volatile("s_waitcnt vmcnt(0)" ::: "memory")
#define LW0 asm volatile("s_waitcnt lgkmcnt(0)" ::: "memory")
#define SBAR __builtin_amdgcn_s_barrier()

// ---------------- weight packing: fp32 Wx/Wh -> bf16 MFMA-B fragments ----------------
// Wp index: ((((l*64 + j)*4 + g)*64 + k0)*64 + lane)*8 + i   (bf16 units)
// lane element i: k = k0*32 + (lane>>4)*8 + i, col h = j*16 + (lane&15)
// rows k<1024 from Wx[l][g], rows >=1024 from Wh[l][g].
__global__ void pack_k(const float* __restrict__ Wx, const float* __restrict__ Wh,
                       unsigned short* __restrict__ Wp) {
  int bid = blockIdx.x;
  int k0 = bid & 63;
  int g = (bid >> 6) & 3;
  int j = (bid >> 8) & 63;
  int l = bid >> 14;
  int lane = threadIdx.x;
  int h = j * 16 + (lane & 15);
  int kb = k0 * 32 + (lane >> 4) * 8;
  const float* src;
  if (kb < 1024) src = Wx + ((size_t)((l * 4 + g) * 1024 + kb)) * 1024 + h;
  else           src = Wh + ((size_t)((l * 4 + g) * 1024 + (kb - 1024))) * 1024 + h;
  unsigned short o[8];
#pragma unroll
  for (int i = 0; i < 8; ++i) o[i] = f2bf(src[(size_t)i * 1024]);
  uint4 v;
  v.x = (unsigned)o[0] | ((unsigned)o[1] << 16);
  v.y = (unsigned)o[2] | ((unsigned)o[3] << 16);
  v.z = (unsigned)o[4] | ((unsigned)o[5] << 16);
  v.w = (unsigned)o[6] | ((unsigned)o[7] << 16);
  *(uint4*)(Wp + (((size_t)bid * 64 + lane) * 8)) = v;
}

// ---------------- embedding gather ----------------
__global__ void embed_k(const int* __restrict__ X, const float* __restrict__ emb,
                        unsigned short* __restrict__ hsA) {
  int sb = blockIdx.x;  // t*64 + b
  int t = sb >> 6, b = sb & 63;
  int row = X[b * SEQL + t];
  float4 v = ((const float4*)(emb + (size_t)row * HID))[threadIdx.x];
  unsigned short o0 = f2bf(v.x), o1 = f2bf(v.y), o2 = f2bf(v.z), o3 = f2bf(v.w);
  uint2 pk;
  pk.x = (unsigned)o0 | ((unsigned)o1 << 16);
  pk.y = (unsigned)o2 | ((unsigned)o3 << 16);
  ((uint2*)(hsA + (size_t)sb * HID))[threadIdx.x] = pk;
}

// ---------------- persistent fused LSTM, weights-in-registers ----------------
// 256 blocks x 512 threads = 1 block/CU. Block (bg, cg): bg = batch-group
// (16 rows), cg = col-group (16 hidden cols). Wave w: gate g = w&3,
// K-half kh = w>>2. Each wave holds its 16-col x 1024-K weight tile in
// 32 s16x8 fragments (128 VGPRs), loaded once per layer.
// Per step: 32 KB h-stage + 32 KB x-prefetch; 32 MFMA/wave; K-half reduce
// through LDS; gates on tid<128; sc1 h-store + per-bg flag barrier (64 blocks).
extern __shared__ char smem[];

// LDS A-buffer: [16 rows][1024 K] bf16, rows 2048 B, 16B-slot XOR-swizzle by row&7.
// Stage: linear LDS dest + inverse-swizzled global source (involution).
__device__ __forceinline__ void stage16(const char* slab, char* lbuf, int srow, int sslot) {
#pragma unroll
  for (int r = 0; r < 4; ++r) {
    int rw = r * 4 + srow;
    llds16(slab + rw * 2048 + ((sslot ^ (rw & 7)) << 4), lbuf + rw * 2048 + sslot * 16);
  }
}

__device__ __forceinline__ void pollflags(const int* fl, int id, int lane) {
  if (id <= 0) return;
  for (;;) {
    int v = __hip_atomic_load(&fl[lane * 4], __ATOMIC_RELAXED, __HIP_MEMORY_SCOPE_AGENT);
    if (__all(v >= id)) break;
    __builtin_amdgcn_s_sleep(1);
  }
}

__global__ void __launch_bounds__(512, 1)
lstm_pers(const unsigned short* __restrict__ Wp, const float* __restrict__ bias,
          unsigned short* hsA, unsigned short* hsB, int* flags) {
  const int bid = blockIdx.x;
  const int bg = bid >> 6;   // batch group 0..3 (16 rows each)
  const int cg = bid & 63;   // col group 0..63 (16 cols each)
  const int tid = threadIdx.x;
  const int wave = tid >> 6;
  const int lane = tid & 63;
  const int g = wave & 3;    // gate
  const int kh = wave >> 2;  // K-half: 0 = x, 1 = h
  const int hl = lane & 15;
  const int ksub = lane >> 4;
  const int srow = tid >> 7;   // staging row-phase 0..3 (wave-uniform)
  const int sslot = tid & 127; // staging 16B slot

  char* Bx0 = smem;                         // 32768
  char* Bx1 = smem + 32768;                 // 32768
  char* Bh = smem + 65536;                  // 32768
  float* pre0 = (float*)(smem + 98304);     // [4][16][17] f32 = 4352
  float* pre1 = (float*)(smem + 102656);    // [4][16][17] f32 = 4352

  int* flbg = flags + bg * 256;  // own batch-group's 64 flags (16B spaced)

  for (int l = 0; l < NLAY; ++l) {
    const unsigned short* hin = (l & 1) ? hsB : hsA;
    unsigned short* hout = (l & 1) ? hsA : hsB;
    const unsigned short* wpL =
        Wp + (size_t)(l * 64 + cg) * 131072 + (size_t)g * 32768 + (size_t)kh * 32 * 512;
    const float biasv = bias[(l * 4 + g) * 1024 + cg * 16 + hl];

    // ---- weights into registers: 32 fragments = 128 VGPRs (static indexing) ----
    s16x8 wreg[32];
#pragma unroll
    for (int i = 0; i < 32; ++i)
      wreg[i] = *(const s16x8*)(wpL + i * 512 + lane * 8);

    float c0 = 0.f, c1 = 0.f;  // cell state (threads 0..127)

    // ---- layer entry: own bg finished layer l-1; then stage x_0, zero Bh ----
    if (wave == 4) pollflags(flbg, l * 256, lane);
    AFENCE; SBAR;
#pragma unroll
    for (int r = 0; r < 4; ++r)
      ((uint4*)Bh)[r * 512 + tid] = (uint4){0u, 0u, 0u, 0u};
    stage16((const char*)hin + (size_t)(bg * 16) * 2048, Bx0, srow, sslot);
    VW0; LW0; SBAR;

    for (int t = 0; t < SEQL; ++t) {
      char* Bxp = (t & 1) ? Bx1 : Bx0;
      char* Bxn = (t & 1) ? Bx0 : Bx1;
      const bool pre_ = (t + 1 < SEQL);

      // phase 1: prefetch x_{t+1} (whole previous layer ready -> no sync needed)
      if (pre_) {
        const char* xn = (const char*)hin + ((size_t)(t + 1) * 64 + bg * 16) * 2048;
        stage16(xn, Bxn, srow, sslot);
      }

      f32x4 acc = {0.f, 0.f, 0.f, 0.f};
      // phase 2: x-half MFMA (kh==0) + pre0 write; wave 4 polls for h_{t-1}
      if (kh == 0) {
#pragma unroll
        for (int i = 0; i < 32; ++i) {
          int off = hl * 2048 + (((i * 4 + ksub) ^ (hl & 7)) << 4);
          s16x8 a = *(const s16x8*)(Bxp + off);
          acc = __builtin_amdgcn_mfma_f32_16x16x32_bf16(a, wreg[i], acc, 0, 0, 0);
        }
#pragma unroll
        for (int r = 0; r < 4; ++r)
          pre0[(g * 16 + ksub * 4 + r) * 17 + hl] = acc[r] + biasv;
      } else if (wave == 4 && t > 0) {
        pollflags(flbg, l * 256 + t, lane);
      }
      AFENCE; SBAR;

      // phase 3: stage h_{t-1}
      if (t > 0) {
        const char* hp = (const char*)hout + ((size_t)(t - 1) * 64 + bg * 16) * 2048;
        stage16(hp, Bh, srow, sslot);
      }
      VW0; SBAR;

      // phase 4: h-half MFMA (kh==1) + pre1 write
      if (kh == 1) {
#pragma unroll
        for (int i = 0; i < 32; ++i) {
          int off = hl * 2048 + (((i * 4 + ksub) ^ (hl & 7)) << 4);
          s16x8 a = *(const s16x8*)(Bh + off);
          acc = __builtin_amdgcn_mfma_f32_16x16x32_bf16(a, wreg[i], acc, 0, 0, 0);
        }
#pragma unroll
        for (int r = 0; r < 4; ++r)
          pre1[(g * 16 + ksub * 4 + r) * 17 + hl] = acc[r];
      }
      LW0; SBAR;

      // phase 5: gates on threads 0..127 (each 1 batch row x 2 cols)
      if (tid < 128) {
        int b = tid >> 3;          // 0..15
        int h0 = (tid & 7) * 2;    // 0..14
        unsigned short hw[2];
#pragma unroll
        for (int q = 0; q < 2; ++q) {
          int hh = h0 + q;
          float pi = pre0[(0 * 16 + b) * 17 + hh] + pre1[(0 * 16 + b) * 17 + hh];
          float pf = pre0[(1 * 16 + b) * 17 + hh] + pre1[(1 * 16 + b) * 17 + hh];
          float po = pre0[(2 * 16 + b) * 17 + hh] + pre1[(2 * 16 + b) * 17 + hh];
          float pg = pre0[(3 * 16 + b) * 17 + hh] + pre1[(3 * 16 + b) * 17 + hh];
          float iv = sigm(pi), fv = sigm(pf), ov = sigm(po), gv = tanh_f(pg);
          float cprev = q ? c1 : c0;
          float c = fv * cprev + iv * gv;
          if (q) c1 = c; else c0 = c;
          hw[q] = f2bf(ov * tanh_f(c));
        }
        unsigned pk = (unsigned)hw[0] | ((unsigned)hw[1] << 16);
        unsigned* dst =
            (unsigned*)(hout + ((size_t)t * 64 + bg * 16 + b) * HID + cg * 16 + h0);
        __hip_atomic_store(dst, pk, __ATOMIC_RELAXED, __HIP_MEMORY_SCOPE_AGENT);
      }
      VW0;   // own h stores acked at coherence point
      SBAR;  // => all waves' h stores globally visible
      if (tid == 0)
        __hip_atomic_store(&flags[(bg * 64 + cg) * 4], l * 256 + t + 1, __ATOMIC_RELAXED,
                           __HIP_MEMORY_SCOPE_AGENT);
    }
  }
}

// ---------------- output projection (fp32, K split 2-way) ----------------
__global__ void __launch_bounds__(256) proj_k(const unsigned short* __restrict__ hlast,
                                              const float* __restrict__ Whq,
                                              float* __restrict__ part) {
  __shared__ float hlds[64 * 128];
  int kh = blockIdx.x / 125;
  int nb = blockIdx.x % 125;
  int n = nb * 256 + threadIdx.x;
  float acc[64];
#pragma unroll
  for (int b = 0; b < 64; ++b) acc[b] = 0.f;
  for (int kc = 0; kc < 4; ++kc) {
    int kbase = kh * 512 + kc * 128;
    __syncthreads();
#pragma unroll
    for (int it = 0; it < 32; ++it) {
      int id = threadIdx.x + it * 256;
      int b = id >> 7, k = id & 127;
      hlds[b * 128 + k] = bf2f(hlast[(size_t)b * HID + kbase + k]);
    }
    __syncthreads();
    for (int k4 = 0; k4 < 32; ++k4) {
      float w0 = Whq[(size_t)(kbase + k4 * 4 + 0) * NCLS + n];
      float w1 = Whq[(size_t)(kbase + k4 * 4 + 1) * NCLS + n];
      float w2 = Whq[(size_t)(kbase + k4 * 4 + 2) * NCLS + n];
      float w3 = Whq[(size_t)(kbase + k4 * 4 + 3) * NCLS + n];
#pragma unroll
      for (int b = 0; b < 64; ++b) {
        float4 h4 = *(const float4*)&hlds[b * 128 + k4 * 4];
        acc[b] += h4.x * w0 + h4.y * w1 + h4.z * w2 + h4.w * w3;
      }
    }
  }
#pragma unroll
  for (int b = 0; b < 64; ++b)
    part[(size_t)kh * 64 * NCLS + (size_t)b * NCLS + n] = acc[b];
}

__global__ void combine_k(const float* __restrict__ part, const float* __restrict__ bq,
                          float* __restrict__ out) {
  int i = blockIdx.x * 256 + threadIdx.x;
  int n = i % NCLS;
  out[i] = part[i] + part[64 * NCLS + i] + bq[n];
}

extern "C" void kernel_launch(void* const* d_in, const int* in_sizes, int n_in,
                              void* d_out, int out_size, void* d_ws, size_t ws_size,
                              hipStream_t stream) {
  const int* X = (const int*)d_in[0];
  const float* emb = (const float*)d_in[1];
  const float* Wx = (const float*)d_in[2];
  const float* Wh = (const float*)d_in[3];
  const float* bias = (const float*)d_in[4];
  const float* Whq = (const float*)d_in[5];
  const float* bq = (const float*)d_in[6];
  float* out = (float*)d_out;
  char* ws = (char*)d_ws;

  const size_t WP_OFF = 0;                      // 83,886,080  packed weights bf16
  const size_t HSA_OFF = 83886080;              // 33,554,432  hs ping
  const size_t HSB_OFF = HSA_OFF + 33554432;    // 33,554,432  hs pong
  const size_t PART_OFF = HSB_OFF + 33554432;   // 16,384,000  proj partials
  const size_t FLAG_OFF = PART_OFF + 16384000;  // 4,096       barrier flags (4 bg x 64 cg x 16B)
  const size_t NEED = FLAG_OFF + 4096;
  if (ws_size < NEED) return;

  unsigned short* Wp = (unsigned short*)(ws + WP_OFF);
  unsigned short* hsA = (unsigned short*)(ws + HSA_OFF);
  unsigned short* hsB = (unsigned short*)(ws + HSB_OFF);
  float* part = (float*)(ws + PART_OFF);
  int* flags = (int*)(ws + FLAG_OFF);

  hipMemsetAsync(flags, 0, 4096, stream);
  pack_k<<<81920, 64, 0, stream>>>(Wx, Wh, Wp);
  embed_k<<<16384, 256, 0, stream>>>(X, emb, hsA);
  (void)hipFuncSetAttribute(reinterpret_cast<const void*>(&lstm_pers),
                            hipFuncAttributeMaxDynamicSharedMemorySize, 107008);
  lstm_pers<<<256, 512, 107008, stream>>>(Wp, bias, hsA, hsB, flags);
  const unsigned short* hlastp = hsB + (size_t)255 * BATCH * HID;  // layer 4, t=255
  proj_k<<<250, 256, 0, stream>>>(hlastp, Whq, part);
  combine_k<<<8000, 256, 0, stream>>>(part, bq, out);
}